// Round 1
// 310.374 us; speedup vs baseline: 1.0009x; 1.0009x over previous
//
#include <hip/hip_runtime.h>

// DLRM InteractionArch: B=16384, D=128, F=26, N=27
// out[b] = concat(dense[b] (128 fp32), triu(X X^T, k=1) (351 fp32)),
// X = concat(dense[b][None,:], sparse[b]) : 27 x 128.
//
// One wave per batch element (4096 blocks x 4 waves = 16384 waves).
// MFMA fragments are loaded DIRECTLY from global memory in A-operand layout
// (lane l <- X[l&31][s*16 + (l>>5)*8 ..+7], two aligned float4 per s; lane
// pairs (l,l+32) cover one 64B line per row -> fully coalesced, zero LDS).
// Rows 27..31 clamp to row 26 (same cachelines, outputs never extracted).
//
// v2 polish: triangle results are stored DIRECTLY to global (no LDS staging,
// no lgkmcnt wait, no wave_barrier). For a fixed acc reg the 64 lanes write
// <=2 contiguous runs inside the fully-written 1.4KB triangle region, so L2
// write-combining reassembles full lines; stores are only 12% of traffic.
// This removes the ~300-cycle LDS round-trip tail between MFMA and wave end.

#define FEAT 26
#define NROW 27
#define DDIM 128
#define NTRI 351            // 27*26/2
#define OUTW 479            // 128 + 351
#define WPB   4
#define GRID  4096          // 4096 * 4 waves = 16384 = B

typedef _Float16 half8v __attribute__((ext_vector_type(8)));
typedef float    f32x16 __attribute__((ext_vector_type(16)));

__global__ __launch_bounds__(256) void interaction_kernel(
    const float* __restrict__ dense,
    const float* __restrict__ sparse,
    float* __restrict__ out)
{
    const int lane = threadIdx.x & 63;
    const int w    = threadIdx.x >> 6;
    const long b   = blockIdx.x * WPB + w;   // 0..16383, one batch per wave

    const int r  = lane & 31;                // fragment row / C-column j0
    const int q  = lane >> 5;
    const int rr = (r > FEAT) ? FEAT : r;    // clamp rows 27..31 -> 26

    const float* dn   = dense  + b * DDIM;
    const float* sp   = sparse + b * (FEAT * DDIM);
    float*       orow = out    + b * OUTW;

    // per-lane fragment row base: row 0 = dense, rows 1..26 = sparse
    const float* rowp = (rr == 0) ? dn : (sp + (rr - 1) * DDIM);

    // ---- load A-fragment straight from global, convert to fp16 (RTN)
    half8v fr[8];
#pragma unroll
    for (int s = 0; s < 8; ++s) {
        const float* p = rowp + s * 16 + q * 8;
        float4 a = *(const float4*)(p);
        float4 c = *(const float4*)(p + 4);
        half8v f;
        f[0] = (_Float16)a.x; f[1] = (_Float16)a.y;
        f[2] = (_Float16)a.z; f[3] = (_Float16)a.w;
        f[4] = (_Float16)c.x; f[5] = (_Float16)c.y;
        f[6] = (_Float16)c.z; f[7] = (_Float16)c.w;
        fr[s] = f;
    }

    // ---- dense row fp32 passthrough (same cachelines as row-0 frags)
    float2 dv = *(const float2*)(dn + lane * 2);

    // ---- Gram: same fragment as A and B -> C = X X^T
    f32x16 acc = {0,0,0,0,0,0,0,0,0,0,0,0,0,0,0,0};
#pragma unroll
    for (int s = 0; s < 8; ++s)
        acc = __builtin_amdgcn_mfma_f32_32x32x16_f16(fr[s], fr[s], acc, 0, 0, 0);

    orow[lane * 2 + 0] = dv.x;
    orow[lane * 2 + 1] = dv.y;

    // ---- extract triu(k=1) directly to global:
    // C/D layout col=lane&31, row=(reg&3)+8*(reg>>2)+4*q  [measured m74/m101]
    // For pair (i<j): q=(i>>2)&1, reg=(i&3)|((i>>3)<<2), lane=q*32+j -> each
    // triangle element is written by exactly one lane of one store.
#pragma unroll
    for (int reg = 0; reg < 16; ++reg) {
        int row = (reg & 3) + 8 * (reg >> 2) + 4 * q;
        if (row < r && r < NROW) {
            int t = row * (2 * NROW - row - 1) / 2 + (r - row - 1);
            orow[DDIM + t] = acc[reg];
        }
    }
}

extern "C" void kernel_launch(void* const* d_in, const int* in_sizes, int n_in,
                              void* d_out, int out_size, void* d_ws, size_t ws_size,
                              hipStream_t stream) {
    const float* dense  = (const float*)d_in[0];
    const float* sparse = (const float*)d_in[1];
    float* out = (float*)d_out;
    interaction_kernel<<<GRID, 256, 0, stream>>>(dense, sparse, out);
}